// Round 4
// baseline (1175.092 us; speedup 1.0000x reference)
//
#include <hip/hip_runtime.h>
#include <math.h>

typedef _Float16 f16;
typedef _Float16 f16x8 __attribute__((ext_vector_type(8)));
typedef float f32x4 __attribute__((ext_vector_type(4)));

#define NSTEP 128
#define FEAT  127
#define BLK_B 16
#define NBLOCK 256
#define NTHREADS 512

// LDS layout (dynamic): wih0 frag table 131072 B | xs [16][136] 4352 B |
// h0s [2][16][136] 8704 B | h1s [2][16][136] 8704 B | outp [8][16] f32 512 B
#define LW_OFF   0
#define XS_OFF   131072
#define H0_OFF   135424
#define H1_OFF   144128
#define OUTP_OFF 152832
#define SMEM_BYTES 153344
#define HSTRIDE 136   // halfs per row: 272 B, 16B-aligned, b128 conflict-optimal

__device__ __forceinline__ float sigf(float x) { return 1.0f / (1.0f + __expf(-x)); }
__device__ __forceinline__ float tanh_(float x) { return 1.0f - 2.0f / (1.0f + __expf(2.0f * x)); }

// f16 MFMA B-fragments in d_ws. Segments sel: 0=w_ih0 1=w_hh0 2=w_ih1 3=w_hh1,
// each 65536 halfs. Fragment (sel,wave,gate,ks,lane) = f16x8 at
//   sel*8192 + ((wave*4+gate)*4+ks)*64 + lane
// holding W[n][k], n = gate*128 + wave*16 + (lane&15), k = ks*32 + (lane>>4)*8 + j.
__global__ void prep_weights(const float* __restrict__ w_ih0,
                             const float* __restrict__ w_hh0,
                             const float* __restrict__ w_ih1,
                             const float* __restrict__ w_hh1,
                             f16* __restrict__ ws16)
{
    int idx = blockIdx.x * blockDim.x + threadIdx.x;  // 0 .. 262143
    int j    = idx & 7;
    int lane = (idx >> 3) & 63;
    int ks   = (idx >> 9) & 3;
    int gate = (idx >> 11) & 3;
    int wave = (idx >> 13) & 7;
    int sel  = (idx >> 16) & 3;
    int n = gate * 128 + wave * 16 + (lane & 15);
    int k = ks * 32 + (lane >> 4) * 8 + j;
    const float* W = (sel == 0) ? w_ih0 : (sel == 1) ? w_hh0 : (sel == 2) ? w_ih1 : w_hh1;
    ws16[idx] = (f16)W[n * 128 + k];
}

#define PIN(v) asm volatile("" : "+v"(v))

// Fused 2-layer LSTM: one block = 16 batch rows, full time loop.
// 8 waves; wave w owns units [16w,16w+16) of BOTH layers.
// Weights: w_hh0/w_ih1/w_hh1 register-resident (48 frags = 192 VGPRs, PINned);
// w_ih0 fragment table in LDS (copied once). h0/h1 handoff via LDS only.
__global__ __launch_bounds__(NTHREADS, 2) void lstm_fused(
    const float* __restrict__ nf,   const float* __restrict__ tgt,
    const float* __restrict__ b_ih0, const float* __restrict__ b_hh0,
    const float* __restrict__ b_ih1, const float* __restrict__ b_hh1,
    const float* __restrict__ w_out, const float* __restrict__ b_out,
    const f16* __restrict__ wfrag,  float* __restrict__ out)
{
    extern __shared__ __align__(16) char smem[];
    f16*   lw   = (f16*)(smem + LW_OFF);     // wih0 frags (8192 x f16x8)
    f16*   xsb  = (f16*)(smem + XS_OFF);     // [16][HSTRIDE]
    f16*   h0b  = (f16*)(smem + H0_OFF);     // [2][16][HSTRIDE]
    f16*   h1b  = (f16*)(smem + H1_OFF);     // [2][16][HSTRIDE]
    float* outp = (float*)(smem + OUTP_OFF); // [8][16]

    const int tid  = threadIdx.x;
    const int wave = tid >> 6;
    const int lane = tid & 63;
    const int col  = lane & 15;
    const int quad = lane >> 4;
    const int b0   = blockIdx.x * BLK_B;
    const int u    = wave * 16 + col;

    const f16x8* wf = (const f16x8*)wfrag;

    // ---- copy wih0 frag table into LDS (8192 frags, 512 threads, 16 iters)
    {
        f16x8* lwv = (f16x8*)lw;
#pragma unroll
        for (int i = 0; i < 16; ++i)
            lwv[i * NTHREADS + tid] = wf[i * NTHREADS + tid];
    }

    // ---- zero h-state (both parity buffers)
    for (int i = tid; i < 2 * 16 * HSTRIDE; i += NTHREADS) {
        h0b[i] = (f16)0.0f;
        h1b[i] = (f16)0.0f;
    }

    float bias0[4], bias1[4];
#pragma unroll
    for (int g = 0; g < 4; ++g) {
        bias0[g] = b_ih0[g * 128 + u] + b_hh0[g * 128 + u];
        bias1[g] = b_ih1[g * 128 + u] + b_hh1[g * 128 + u];
    }
    const float wo_u = w_out[u];
    const float bout = b_out[0];

    // ---- persistent fragments: 48 x f16x8 = 192 VGPRs, pinned
    f16x8 whh0[4][4], wih1[4][4], whh1[4][4];
#pragma unroll
    for (int g = 0; g < 4; ++g)
#pragma unroll
        for (int ks = 0; ks < 4; ++ks) {
            const int fi = ((wave * 4 + g) * 4 + ks) * 64 + lane;
            whh0[g][ks] = wf[1 * 8192 + fi];
            wih1[g][ks] = wf[2 * 8192 + fi];
            whh1[g][ks] = wf[3 * 8192 + fi];
            PIN(whh0[g][ks]);
            PIN(wih1[g][ks]);
            PIN(whh1[g][ks]);
        }

    f32x4 c0 = {0.f, 0.f, 0.f, 0.f};
    f32x4 c1 = {0.f, 0.f, 0.f, 0.f};

    // ---- stage x(0): wave w loads rows 2w, 2w+1; k = lane, lane+64
#pragma unroll
    for (int rr = 0; rr < 2; ++rr) {
        const int row = wave * 2 + rr;
        const long gbt = (long)(b0 + row) * NSTEP;
#pragma unroll
        for (int h = 0; h < 2; ++h) {
            const int k = lane + 64 * h;
            xsb[row * HSTRIDE + k] = (f16)((k < FEAT) ? nf[gbt * FEAT + k] : 0.0f);
        }
    }
    __syncthreads();

    for (int t = 0; t < NSTEP; ++t) {
        const int pa = t & 1, wb = pa ^ 1;

        // ---- prefetch x(t+1) into registers (consumed in phase B)
        float xnv[2][2];
        if (t < NSTEP - 1) {
#pragma unroll
            for (int rr = 0; rr < 2; ++rr) {
                const int row = wave * 2 + rr;
#pragma unroll
                for (int h = 0; h < 2; ++h) {
                    const int k = lane + 64 * h;
                    const long gbt = (long)(b0 + row) * NSTEP + (t + 1);
                    xnv[rr][h] = (k < FEAT) ? nf[gbt * FEAT + k]
                                            : tgt[(long)(b0 + row) * NSTEP + t];
                }
            }
        } else {
            xnv[0][0] = xnv[0][1] = xnv[1][0] = xnv[1][1] = 0.0f;
        }

        // ================= phase A: layer 0 =================
        f32x4 acc[4];
#pragma unroll
        for (int g = 0; g < 4; ++g)
            acc[g] = (f32x4){bias0[g], bias0[g], bias0[g], bias0[g]};
#pragma unroll
        for (int ks = 0; ks < 4; ++ks) {
            f16x8 ax = *(const f16x8*)&xsb[col * HSTRIDE + ks * 32 + quad * 8];
            f16x8 ah = *(const f16x8*)&h0b[pa * 16 * HSTRIDE + col * HSTRIDE + ks * 32 + quad * 8];
#pragma unroll
            for (int g = 0; g < 4; ++g) {
                f16x8 bw = ((const f16x8*)lw)[((wave * 4 + g) * 4 + ks) * 64 + lane];
                acc[g] = __builtin_amdgcn_mfma_f32_16x16x32_f16(ax, bw, acc[g], 0, 0, 0);
                acc[g] = __builtin_amdgcn_mfma_f32_16x16x32_f16(ah, whh0[g][ks], acc[g], 0, 0, 0);
            }
        }
        float h0n[4];
#pragma unroll
        for (int r = 0; r < 4; ++r) {
            const float ig = sigf(acc[0][r]);
            const float fg = sigf(acc[1][r]);
            const float gg = tanh_(acc[2][r]);
            const float og = sigf(acc[3][r]);
            const float cn = fg * c0[r] + ig * gg;
            c0[r] = cn;
            h0n[r] = og * tanh_(cn);
        }
#pragma unroll
        for (int r = 0; r < 4; ++r)
            h0b[wb * 16 * HSTRIDE + (quad * 4 + r) * HSTRIDE + u] = (f16)h0n[r];

        __syncthreads();  // barrier 1: h0(t) visible to all waves

        // ================= phase B: layer 1 + output =================
#pragma unroll
        for (int g = 0; g < 4; ++g)
            acc[g] = (f32x4){bias1[g], bias1[g], bias1[g], bias1[g]};
#pragma unroll
        for (int ks = 0; ks < 4; ++ks) {
            f16x8 a0 = *(const f16x8*)&h0b[wb * 16 * HSTRIDE + col * HSTRIDE + ks * 32 + quad * 8];
            f16x8 a1 = *(const f16x8*)&h1b[pa * 16 * HSTRIDE + col * HSTRIDE + ks * 32 + quad * 8];
#pragma unroll
            for (int g = 0; g < 4; ++g) {
                acc[g] = __builtin_amdgcn_mfma_f32_16x16x32_f16(a0, wih1[g][ks], acc[g], 0, 0, 0);
                acc[g] = __builtin_amdgcn_mfma_f32_16x16x32_f16(a1, whh1[g][ks], acc[g], 0, 0, 0);
            }
        }
        float h1n[4];
#pragma unroll
        for (int r = 0; r < 4; ++r) {
            const float ig = sigf(acc[0][r]);
            const float fg = sigf(acc[1][r]);
            const float gg = tanh_(acc[2][r]);
            const float og = sigf(acc[3][r]);
            const float cn = fg * c1[r] + ig * gg;
            c1[r] = cn;
            h1n[r] = og * tanh_(cn);
        }
#pragma unroll
        for (int r = 0; r < 4; ++r)
            h1b[wb * 16 * HSTRIDE + (quad * 4 + r) * HSTRIDE + u] = (f16)h1n[r];

        // stage prefetched x(t+1) (xs single-buffered: all reads were in phase A)
#pragma unroll
        for (int rr = 0; rr < 2; ++rr) {
            const int row = wave * 2 + rr;
#pragma unroll
            for (int h = 0; h < 2; ++h)
                xsb[row * HSTRIDE + lane + 64 * h] = (f16)xnv[rr][h];
        }

        // output partial: sum over this wave's 16 units
        float ps[4];
#pragma unroll
        for (int r = 0; r < 4; ++r) ps[r] = h1n[r] * wo_u;
#pragma unroll
        for (int m = 1; m < 16; m <<= 1) {
#pragma unroll
            for (int r = 0; r < 4; ++r) ps[r] += __shfl_xor(ps[r], m, 64);
        }
        if (col == 0) {
#pragma unroll
            for (int r = 0; r < 4; ++r) outp[wave * 16 + quad * 4 + r] = ps[r];
        }

        __syncthreads();  // barrier 2: h1(t), xs(t+1), partials visible

        if (tid < 16) {
            float s = bout;
#pragma unroll
            for (int w = 0; w < 8; ++w) s += outp[w * 16 + tid];
            out[(long)(b0 + tid) * NSTEP + t] = sigf(s);
        }
    }
}

extern "C" void kernel_launch(void* const* d_in, const int* in_sizes, int n_in,
                              void* d_out, int out_size, void* d_ws, size_t ws_size,
                              hipStream_t stream)
{
    const float* nf    = (const float*)d_in[0];
    const float* tgt   = (const float*)d_in[1];
    const float* w_ih0 = (const float*)d_in[2];
    const float* w_hh0 = (const float*)d_in[3];
    const float* b_ih0 = (const float*)d_in[4];
    const float* b_hh0 = (const float*)d_in[5];
    const float* w_ih1 = (const float*)d_in[6];
    const float* w_hh1 = (const float*)d_in[7];
    const float* b_ih1 = (const float*)d_in[8];
    const float* b_hh1 = (const float*)d_in[9];
    const float* w_out = (const float*)d_in[10];
    const float* b_out = (const float*)d_in[11];

    f16*   ws16 = (f16*)d_ws;   // 512 KB fragment table
    float* out  = (float*)d_out;

    prep_weights<<<1024, 256, 0, stream>>>(w_ih0, w_hh0, w_ih1, w_hh1, ws16);

    // opt into >64KB dynamic LDS (sticky per-function attribute; harmless if repeated)
    static int lds_set = 0;
    if (!lds_set) {
        hipFuncSetAttribute((const void*)lstm_fused,
                            hipFuncAttributeMaxDynamicSharedMemorySize, SMEM_BYTES);
        lds_set = 1;
    }

    lstm_fused<<<NBLOCK, NTHREADS, SMEM_BYTES, stream>>>(
        nf, tgt, b_ih0, b_hh0, b_ih1, b_hh1, w_out, b_out, ws16, out);
}